// Round 6
// baseline (163.978 us; speedup 1.0000x reference)
//
#include <hip/hip_runtime.h>
#include <math.h>

// mLSTM parallel closed form:
//   F_t = prefix_sum(log_sigmoid(f)),  b_s = i_s - F_s,
//   M_t = max(0, prefix_max(b)_t),  m_t = F_t + M_t,
//   w[t,s] = exp(b_s - M_t)  (s <= t, always <= 1),
//   h_t = (sum_s w*(q.k_s)*v_s) / (max(|sum_s w*(q.k_s)|, exp(-m_t)) + 1e-6)
//
// R5: QT=64 per block (2x arithmetic intensity vs R4), double-buffered LDS
// with early-issue global_load_lds staging, merged prep kernel (3 launches).
// Split-fp16 MFMA (x = hi+lo, 3 mfma per fp32 product), swapped QK^T so P
// stays in-register as PV's A-operand.

typedef _Float16 f16;
typedef _Float16 f16x4 __attribute__((ext_vector_type(4)));
typedef _Float16 f16x8 __attribute__((ext_vector_type(8)));
typedef float    f32x4 __attribute__((ext_vector_type(4)));

#define S_LEN  2048
#define DHD    128
#define NHEADS 8
#define EPS    1e-6f

// LDS: two 64KB buffers (KHI 0 | KLO 16K | VHI 32K | VLO 48K each) + qnl
#define BUFSZ   65536
#define QNL_OFF 131072
#define SMEM_BYTES 131584

__device__ __forceinline__ int kswz(int row, int byteInRow) {
  // 256B rows: XOR row bits into 16B-granule index -> conflict-spread b128 reads
  return row * 256 + (byteInRow ^ ((row & 15) << 4));
}
__device__ __forceinline__ f32x4 mfma16(f16x8 a, f16x8 b, f32x4 c) {
  return __builtin_amdgcn_mfma_f32_16x16x32_f16(a, b, c, 0, 0, 0);
}
__device__ __forceinline__ void gload16(const void* g, void* l) {
  __builtin_amdgcn_global_load_lds((const __attribute__((address_space(1))) unsigned int*)g,
                                   (__attribute__((address_space(3))) unsigned int*)l, 16, 0, 0);
}

// ---------------- scan prepass: b_s, M_t, exp(-m_t) (fp64 internal) --------
__global__ __launch_bounds__(256) void mlstm_scan(
    const float* __restrict__ ig_all, const float* __restrict__ fg_all,
    float* __restrict__ bf, float* __restrict__ Mf, float* __restrict__ en)
{
  const int hd  = blockIdx.x;
  const int tid = threadIdx.x;
  __shared__ double sc[256];
  const float* fg = fg_all + (size_t)hd * S_LEN;
  const float* ig = ig_all + (size_t)hd * S_LEN;
  const int base = tid * 8;

  double v[8];
#pragma unroll
  for (int u = 0; u < 8; ++u) {
    float x = fg[base + u];
    float fl = fminf(x, 0.0f) - log1pf(expf(-fabsf(x)));  // stable log_sigmoid
    v[u] = (double)fl;
  }
#pragma unroll
  for (int u = 1; u < 8; ++u) v[u] += v[u - 1];
  sc[tid] = v[7];
  __syncthreads();
  for (int off = 1; off < 256; off <<= 1) {
    double t = (tid >= off) ? sc[tid - off] : 0.0;
    __syncthreads();
    sc[tid] += t;
    __syncthreads();
  }
  const double excl = sc[tid] - v[7];

  double F[8], b[8];
#pragma unroll
  for (int u = 0; u < 8; ++u) {
    F[u] = v[u] + excl;
    b[u] = (double)ig[base + u] - F[u];
    bf[(size_t)hd * S_LEN + base + u] = (float)b[u];
  }
  __syncthreads();
  double mv[8];
  mv[0] = b[0];
#pragma unroll
  for (int u = 1; u < 8; ++u) mv[u] = fmax(mv[u - 1], b[u]);
  sc[tid] = mv[7];
  __syncthreads();
  for (int off = 1; off < 256; off <<= 1) {
    double t = (tid >= off) ? sc[tid - off] : -1.0e300;
    __syncthreads();
    sc[tid] = fmax(sc[tid], t);
    __syncthreads();
  }
  const double exclm = (tid > 0) ? sc[tid - 1] : -1.0e300;
  double run = exclm;
#pragma unroll
  for (int u = 0; u < 8; ++u) {
    run = fmax(run, b[u]);
    double Mt = fmax(0.0, run);       // m0=0 carry path
    Mf[(size_t)hd * S_LEN + base + u] = (float)Mt;
    en[(size_t)hd * S_LEN + base + u] = (float)exp(-(F[u] + Mt));
  }
}

// ---------------- merged prep: K -> hi/lo panels; V -> transposed hi/lo ----
__global__ __launch_bounds__(256) void mlstm_prep(
    const float* __restrict__ kg, const float* __restrict__ vg,
    char* __restrict__ gkh, char* __restrict__ gkl,
    char* __restrict__ gvh, char* __restrict__ gvl)
{
  __shared__ float vts[64][132];
  const int bid = blockIdx.x;
  const int tid = threadIdx.x;

  if (bid < 256) {
    // ---- K part: row-major hi/lo, swizzled 16B granules ----
    const int gid  = bid * 256 + tid;
    const int row  = gid >> 2;          // head*2048 + kv
    const int part = gid & 3;
    const float* src = kg + (size_t)row * DHD;
    char* oh = gkh + (size_t)row * 256;
    char* ol = gkl + (size_t)row * 256;
#pragma unroll
    for (int j = 0; j < 8; ++j) {
      float4 x = *(const float4*)(src + j * 16 + part * 4);
      float xs[4] = {x.x, x.y, x.z, x.w};
      f16x4 hi, lo;
#pragma unroll
      for (int s = 0; s < 4; ++s) { f16 h = (f16)xs[s]; hi[s] = h; lo[s] = (f16)(xs[s] - (float)h); }
      const int byte = (j * 32 + part * 8) ^ ((row & 15) << 4);
      *(f16x4*)(oh + byte) = hi;
      *(f16x4*)(ol + byte) = lo;
    }
  } else {
    // ---- V part: transpose to [e][kv] hi/lo, swizzled 8B granules ----
    const int b2   = bid - 256;          // 8 heads x 32 tiles
    const int head = b2 >> 5;
    const int it   = b2 & 31;
    {
      const int r   = tid >> 2;
      const int seg = tid & 3;
      const float* src = vg + ((size_t)(head * S_LEN + it * 64 + r)) * DHD;
#pragma unroll
      for (int j = 0; j < 8; ++j) {
        const int c4 = j * 16 + seg * 4;
        *(float4*)&vts[r][c4] = *(const float4*)(src + c4);
      }
    }
    __syncthreads();
    const int e = tid >> 1;
    const int h = tid & 1;
    const size_t tb = (size_t)(head * 32 + it) * 16384 + (size_t)e * 128;
#pragma unroll
    for (int i4 = 0; i4 < 8; ++i4) {
      f16x4 hi, lo;
#pragma unroll
      for (int s = 0; s < 4; ++s) {
        float x = vts[32 * h + i4 * 4 + s][e];
        f16 hh = (f16)x; hi[s] = hh; lo[s] = (f16)(x - (float)hh);
      }
      const int byte = ((32 * h + i4 * 4) * 2) ^ ((e & 15) << 3);
      *(f16x4*)(gvh + tb + byte) = hi;
      *(f16x4*)(gvl + tb + byte) = lo;
    }
  }
}

// ---------------- main kernel: QT=64, KT=64, double-buffered staging -------
__global__ __launch_bounds__(256, 1) void mlstm_fast2(
    const float* __restrict__ qg,
    const char* __restrict__ gkh, const char* __restrict__ gkl,
    const char* __restrict__ gvh, const char* __restrict__ gvl,
    const float* __restrict__ bf, const float* __restrict__ Mf,
    const float* __restrict__ en, float* __restrict__ outg)
{
  extern __shared__ char smem[];
  const int bid  = blockIdx.x;
  const int hd   = bid & 7;            // head i -> XCD i (L2-resident panels)
  const int j    = bid >> 3;           // q-tile 0..31 (64 rows)
  const int t0   = j * 64;
  const int tid  = threadIdx.x;
  const int w    = tid >> 6;
  const int lane = tid & 63;
  const int c    = lane & 15;
  const int g    = lane >> 4;
  const int wk   = w & 1;              // kv half (32 rows)
  const int qp   = w >> 1;             // q-subtile pair: {2qp, 2qp+1}

  const size_t hbase = (size_t)hd * S_LEN;
  const char* pkh = gkh + hbase * 256;         // per-head K panel (512KB)
  const char* pkl = gkl + hbase * 256;
  const char* pvh = gvh + (size_t)hd * 524288; // per-head VT panel (512KB)
  const char* pvl = gvl + (size_t)hd * 524288;

  const int n_it = j + 1;

  // ---- prologue: issue first stage, then Q fragments ----
  {
    const size_t tb = 0;
#pragma unroll
    for (int u = 0; u < 4; ++u) {
      const int off = (w << 12) + (u << 10);
      const int gl  = off + lane * 16;
      gload16(pkh + tb + gl, smem + 0     + off);
      gload16(pkl + tb + gl, smem + 16384 + off);
      gload16(pvh + tb + gl, smem + 32768 + off);
      gload16(pvl + tb + gl, smem + 49152 + off);
    }
  }

  constexpr float QSC = 0.08838834764831845f;
  f16x8 qfh[2][4], qfl[2][4];
#pragma unroll
  for (int u = 0; u < 2; ++u) {
    const float* qrow = qg + (hbase + t0 + 16 * (2 * qp + u) + c) * DHD;
#pragma unroll
    for (int kc = 0; kc < 4; ++kc) {
      const float* p = qrow + kc * 32 + 8 * g;
      float4 a = *(const float4*)p;
      float4 b = *(const float4*)(p + 4);
      float xs[8] = {a.x, a.y, a.z, a.w, b.x, b.y, b.z, b.w};
#pragma unroll
      for (int s = 0; s < 8; ++s) {
        float x = xs[s] * QSC;
        f16 hi = (f16)x;
        qfh[u][kc][s] = hi;
        qfl[u][kc][s] = (f16)(x - (float)hi);
      }
    }
  }
  float Mq[2];
  Mq[0] = Mf[hbase + t0 + 16 * (2 * qp) + c];
  Mq[1] = Mf[hbase + t0 + 16 * (2 * qp + 1) + c];

  const f32x4 z4 = {0.f, 0.f, 0.f, 0.f};
  f32x4 hacc[2][8];
#pragma unroll
  for (int u = 0; u < 2; ++u)
#pragma unroll
    for (int et = 0; et < 8; ++et) hacc[u][et] = z4;
  float qn[2] = {0.f, 0.f};

  int cur = 0;
  for (int it = 0; it < n_it; ++it) {
    const int s0 = it * 64;
    __syncthreads();   // drains own vmem (staged cur complete) + publishes LDS

    // b values for this iter (issued before next stage -> cheap counted wait)
    f32x4 b0 = *(const f32x4*)(bf + hbase + s0 + 32 * wk + 4 * g);
    f32x4 b1 = *(const f32x4*)(bf + hbase + s0 + 32 * wk + 16 + 4 * g);

    // ---- early-issue next tile into the other buffer ----
    if (it + 1 < n_it) {
      const size_t tb = (size_t)(it + 1) * 16384;
      char* lb = smem + (cur ^ 1) * BUFSZ;
#pragma unroll
      for (int u = 0; u < 4; ++u) {
        const int off = (w << 12) + (u << 10);
        const int gl  = off + lane * 16;
        gload16(pkh + tb + gl, lb + 0     + off);
        gload16(pkl + tb + gl, lb + 16384 + off);
        gload16(pvh + tb + gl, lb + 32768 + off);
        gload16(pvl + tb + gl, lb + 49152 + off);
      }
    }

    const char* lb = smem + cur * BUFSZ;

    // ---- swapped QK^T: D = mfma(K, Q); lane: q=c, kv=32wk+{4g+r,16+4g+r} --
    f32x4 sacc[2][2];
    sacc[0][0] = z4; sacc[0][1] = z4; sacc[1][0] = z4; sacc[1][1] = z4;
#pragma unroll
    for (int kc = 0; kc < 4; ++kc) {
      const int cb = kc * 64 + 16 * g;
      f16x8 kh0 = *(const f16x8*)(lb + 0     + kswz(32 * wk + c,      cb));
      f16x8 kl0 = *(const f16x8*)(lb + 16384 + kswz(32 * wk + c,      cb));
      f16x8 kh1 = *(const f16x8*)(lb + 0     + kswz(32 * wk + 16 + c, cb));
      f16x8 kl1 = *(const f16x8*)(lb + 16384 + kswz(32 * wk + 16 + c, cb));
#pragma unroll
      for (int u = 0; u < 2; ++u) {
        sacc[u][0] = mfma16(kh0, qfh[u][kc], sacc[u][0]);
        sacc[u][0] = mfma16(kh0, qfl[u][kc], sacc[u][0]);
        sacc[u][0] = mfma16(kl0, qfh[u][kc], sacc[u][0]);
        sacc[u][1] = mfma16(kh1, qfh[u][kc], sacc[u][1]);
        sacc[u][1] = mfma16(kh1, qfl[u][kc], sacc[u][1]);
        sacc[u][1] = mfma16(kl1, qfh[u][kc], sacc[u][1]);
      }
    }

    // ---- P = exp(b_s - M_q) * S, causal mask, split to fp16 frags ----
    f16x8 pfh[2], pfl[2];
#pragma unroll
    for (int u = 0; u < 2; ++u) {
      const int qglob = t0 + 16 * (2 * qp + u) + c;
#pragma unroll
      for (int r = 0; r < 4; ++r) {
        const int kv0 = s0 + 32 * wk + 4 * g + r;
        const int kv1 = kv0 + 16;
        float p0 = (kv0 <= qglob) ? __expf(b0[r] - Mq[u]) * sacc[u][0][r] : 0.f;
        float p1 = (kv1 <= qglob) ? __expf(b1[r] - Mq[u]) * sacc[u][1][r] : 0.f;
        qn[u] += p0 + p1;
        f16 h0 = (f16)p0; pfh[u][r]     = h0; pfl[u][r]     = (f16)(p0 - (float)h0);
        f16 h1 = (f16)p1; pfh[u][r + 4] = h1; pfl[u][r + 4] = (f16)(p1 - (float)h1);
      }
    }

    // ---- PV: A = P (in-register), B = V^T frags from LDS ----
    const int byte0 = (64 * wk + 8 * g)      ^ (c << 3);
    const int byte1 = (64 * wk + 32 + 8 * g) ^ (c << 3);
#pragma unroll
    for (int et = 0; et < 8; ++et) {
      const int eb = (16 * et + c) * 128;
      f16x4 vh0 = *(const f16x4*)(lb + 32768 + eb + byte0);
      f16x4 vh1 = *(const f16x4*)(lb + 32768 + eb + byte1);
      f16x4 vl0 = *(const f16x4*)(lb + 49152 + eb + byte0);
      f16x4 vl1 = *(const f16x4*)(lb + 49152 + eb + byte1);
      f16x8 vfh, vfl;
#pragma unroll
      for (int s = 0; s < 4; ++s) {
        vfh[s] = vh0[s]; vfh[s + 4] = vh1[s];
        vfl[s] = vl0[s]; vfl[s + 4] = vl1[s];
      }
#pragma unroll
      for (int u = 0; u < 2; ++u) {
        hacc[u][et] = mfma16(pfh[u], vfh, hacc[u][et]);
        hacc[u][et] = mfma16(pfh[u], vfl, hacc[u][et]);
        hacc[u][et] = mfma16(pfl[u], vfh, hacc[u][et]);
      }
    }
    cur ^= 1;
  }

  // ---- epilogue: reduce across wk halves, normalize, store ----
#pragma unroll
  for (int u = 0; u < 2; ++u) {
    qn[u] += __shfl_xor(qn[u], 16);
    qn[u] += __shfl_xor(qn[u], 32);
  }
  __syncthreads();   // all fragment reads done before repurposing buffers
  float* qnl  = (float*)(smem + QNL_OFF);
  float* part = (float*)smem;          // [2 wk][64 q][132]
  if (lane < 16) {
    qnl[(wk * 4 + 2 * qp + 0) * 16 + lane] = qn[0];
    qnl[(wk * 4 + 2 * qp + 1) * 16 + lane] = qn[1];
  }
#pragma unroll
  for (int u = 0; u < 2; ++u)
#pragma unroll
    for (int et = 0; et < 8; ++et)
#pragma unroll
      for (int r = 0; r < 4; ++r)
        part[(wk * 64 + 16 * (2 * qp + u) + 4 * g + r) * 132 + 16 * et + c] = hacc[u][et][r];
  __syncthreads();

  const int e4 = (tid & 31) * 4;
#pragma unroll
  for (int pass = 0; pass < 8; ++pass) {
    const int q = pass * 8 + (tid >> 5);
    const float* pa = part + q * 132 + e4;
    const float* pb = part + (64 + q) * 132 + e4;
    f32x4 s;
#pragma unroll
    for (int s_ = 0; s_ < 4; ++s_) s[s_] = pa[s_] + pb[s_];
    const float qns = qnl[(q >> 4) * 16 + (q & 15)] + qnl[(4 + (q >> 4)) * 16 + (q & 15)];
    const float den = fmaxf(fabsf(qns), en[hbase + t0 + q]) + EPS;
    const float inv = 1.0f / den;
    float4 o = make_float4(s[0] * inv, s[1] * inv, s[2] * inv, s[3] * inv);
    *(float4*)(outg + (hbase + t0 + q) * DHD + e4) = o;
  }
}

extern "C" void kernel_launch(void* const* d_in, const int* in_sizes, int n_in,
                              void* d_out, int out_size, void* d_ws, size_t ws_size,
                              hipStream_t stream) {
  (void)in_sizes; (void)n_in; (void)out_size; (void)ws_size;
  const float* q  = (const float*)d_in[0];
  const float* k  = (const float*)d_in[1];
  const float* v  = (const float*)d_in[2];
  const float* ii = (const float*)d_in[3];
  const float* ff = (const float*)d_in[4];
  float* out = (float*)d_out;

  float* bf = (float*)d_ws;                 // f32 [8][2048]
  float* Mf = bf + NHEADS * S_LEN;
  float* en = Mf + NHEADS * S_LEN;          // ends at 192KB

  const size_t PANEL = 4u * 1024 * 1024;    // 4MB per panel
  char* gkh = (char*)(en + NHEADS * S_LEN);
  char* gkl = gkh + PANEL;
  char* gvh = gkl + PANEL;
  char* gvl = gvh + PANEL;

  hipFuncSetAttribute(reinterpret_cast<const void*>(mlstm_fast2),
                      hipFuncAttributeMaxDynamicSharedMemorySize, SMEM_BYTES);
  mlstm_scan<<<dim3(NHEADS), dim3(256), 0, stream>>>(ii, ff, bf, Mf, en);
  mlstm_prep<<<dim3(512), dim3(256), 0, stream>>>(k, v, gkh, gkl, gvh, gvl);
  mlstm_fast2<<<dim3(256), dim3(256), SMEM_BYTES, stream>>>(
      q, gkh, gkl, gvh, gvl, bf, Mf, en, out);
}

// Round 7
// 136.299 us; speedup vs baseline: 1.2031x; 1.2031x over previous
//
#include <hip/hip_runtime.h>
#include <math.h>

// mLSTM parallel closed form:
//   F_t = prefix_sum(log_sigmoid(f)),  b_s = i_s - F_s,
//   M_t = max(0, prefix_max(b)_t),  m_t = F_t + M_t,
//   w[t,s] = exp(b_s - M_t)  (s <= t, always <= 1),
//   h_t = (sum_s w*(q.k_s)*v_s) / (max(|sum_s w*(q.k_s)|, exp(-m_t)) + 1e-6)
//
// R6: balanced chunk-split (17/16 iters per CU vs R5's worst-case 32) with a
// small merge kernel for split tiles; single 64KB LDS buffer -> 2 blocks/CU
// (2 waves/SIMD latency hiding + cross-block staging/compute overlap);
// scan+prep fused into one kernel. Split-fp16 MFMA engine unchanged from R5.

typedef _Float16 f16;
typedef _Float16 f16x4 __attribute__((ext_vector_type(4)));
typedef _Float16 f16x8 __attribute__((ext_vector_type(8)));
typedef float    f32x4 __attribute__((ext_vector_type(4)));

#define S_LEN  2048
#define DHD    128
#define NHEADS 8
#define EPS    1e-6f

// main-kernel LDS map (single buffer)
#define KHI 0          // fp16 [64][128] K hi, swizzled rows (256B)
#define KLO 16384
#define VHI 32768      // fp16 [128 e][64 kv] V^T hi, swizzled rows (128B)
#define VLO 49152
#define QNL_OFF 65536  // f32 [2 wk][2 u][16]
#define SMEM_MAIN 66048

__device__ __forceinline__ int kswz(int row, int byteInRow) {
  return row * 256 + (byteInRow ^ ((row & 15) << 4));
}
__device__ __forceinline__ f32x4 mfma16(f16x8 a, f16x8 b, f32x4 c) {
  return __builtin_amdgcn_mfma_f32_16x16x32_f16(a, b, c, 0, 0, 0);
}
__device__ __forceinline__ void gload16(const void* g, void* l) {
  __builtin_amdgcn_global_load_lds((const __attribute__((address_space(1))) unsigned int*)g,
                                   (__attribute__((address_space(3))) unsigned int*)l, 16, 0, 0);
}

// ------------- fused prepass: K/V panel conversion + gate scan -------------
// blocks 0..255: K -> hi/lo swizzled panels; 256..511: V -> transposed hi/lo;
// 512..519: per-head fp64 gate scan (b_s, M_t, exp(-m_t)).
__global__ __launch_bounds__(256) void mlstm_pre(
    const float* __restrict__ kg, const float* __restrict__ vg,
    const float* __restrict__ ig_all, const float* __restrict__ fg_all,
    char* __restrict__ gkh, char* __restrict__ gkl,
    char* __restrict__ gvh, char* __restrict__ gvl,
    float* __restrict__ bf, float* __restrict__ Mf, float* __restrict__ en)
{
  __shared__ float vts[64][132];
  __shared__ double sc[256];
  const int bid = blockIdx.x;
  const int tid = threadIdx.x;

  if (bid < 256) {
    // ---- K: row-major hi/lo, swizzled 16B granules ----
    const int gid  = bid * 256 + tid;
    const int row  = gid >> 2;          // head*2048 + kv
    const int part = gid & 3;
    const float* src = kg + (size_t)row * DHD;
    char* oh = gkh + (size_t)row * 256;
    char* ol = gkl + (size_t)row * 256;
#pragma unroll
    for (int j = 0; j < 8; ++j) {
      float4 x = *(const float4*)(src + j * 16 + part * 4);
      float xs[4] = {x.x, x.y, x.z, x.w};
      f16x4 hi, lo;
#pragma unroll
      for (int s = 0; s < 4; ++s) { f16 h = (f16)xs[s]; hi[s] = h; lo[s] = (f16)(xs[s] - (float)h); }
      const int byte = (j * 32 + part * 8) ^ ((row & 15) << 4);
      *(f16x4*)(oh + byte) = hi;
      *(f16x4*)(ol + byte) = lo;
    }
  } else if (bid < 512) {
    // ---- V: transpose to [e][kv] hi/lo, swizzled 8B granules ----
    const int b2   = bid - 256;          // 8 heads x 32 tiles
    const int head = b2 >> 5;
    const int it   = b2 & 31;
    {
      const int r   = tid >> 2;
      const int seg = tid & 3;
      const float* src = vg + ((size_t)(head * S_LEN + it * 64 + r)) * DHD;
#pragma unroll
      for (int j = 0; j < 8; ++j) {
        const int c4 = j * 16 + seg * 4;
        *(float4*)&vts[r][c4] = *(const float4*)(src + c4);
      }
    }
    __syncthreads();
    const int e = tid >> 1;
    const int h = tid & 1;
    const size_t tb = (size_t)(head * 32 + it) * 16384 + (size_t)e * 128;
#pragma unroll
    for (int i4 = 0; i4 < 8; ++i4) {
      f16x4 hi, lo;
#pragma unroll
      for (int s = 0; s < 4; ++s) {
        float x = vts[32 * h + i4 * 4 + s][e];
        f16 hh = (f16)x; hi[s] = hh; lo[s] = (f16)(x - (float)hh);
      }
      const int byte = ((32 * h + i4 * 4) * 2) ^ ((e & 15) << 3);
      *(f16x4*)(gvh + tb + byte) = hi;
      *(f16x4*)(gvl + tb + byte) = lo;
    }
  } else {
    // ---- gate scan (fp64 internal) ----
    const int hd = bid - 512;
    const float* fg = fg_all + (size_t)hd * S_LEN;
    const float* ig = ig_all + (size_t)hd * S_LEN;
    const int base = tid * 8;
    double v[8];
#pragma unroll
    for (int u = 0; u < 8; ++u) {
      float x = fg[base + u];
      float fl = fminf(x, 0.0f) - log1pf(expf(-fabsf(x)));  // stable log_sigmoid
      v[u] = (double)fl;
    }
#pragma unroll
    for (int u = 1; u < 8; ++u) v[u] += v[u - 1];
    sc[tid] = v[7];
    __syncthreads();
    for (int off = 1; off < 256; off <<= 1) {
      double t = (tid >= off) ? sc[tid - off] : 0.0;
      __syncthreads();
      sc[tid] += t;
      __syncthreads();
    }
    const double excl = sc[tid] - v[7];
    double F[8], b[8];
#pragma unroll
    for (int u = 0; u < 8; ++u) {
      F[u] = v[u] + excl;
      b[u] = (double)ig[base + u] - F[u];
      bf[(size_t)hd * S_LEN + base + u] = (float)b[u];
    }
    __syncthreads();
    double mv[8];
    mv[0] = b[0];
#pragma unroll
    for (int u = 1; u < 8; ++u) mv[u] = fmax(mv[u - 1], b[u]);
    sc[tid] = mv[7];
    __syncthreads();
    for (int off = 1; off < 256; off <<= 1) {
      double t = (tid >= off) ? sc[tid - off] : -1.0e300;
      __syncthreads();
      sc[tid] = fmax(sc[tid], t);
      __syncthreads();
    }
    const double exclm = (tid > 0) ? sc[tid - 1] : -1.0e300;
    double run = exclm;
#pragma unroll
    for (int u = 0; u < 8; ++u) {
      run = fmax(run, b[u]);
      double Mt = fmax(0.0, run);       // m0=0 carry path
      Mf[(size_t)hd * S_LEN + base + u] = (float)Mt;
      en[(size_t)hd * S_LEN + base + u] = (float)exp(-(F[u] + Mt));
    }
  }
}

// ---------------- main kernel: QT=64, KT=64, balanced chunks ---------------
// split mode (grid 384): bid<128: tile j=bid>>3, iters [0,j+1), DIRECT.
//   128..255: tile 31-jj, iters [0,16), RAW -> d_out + qn0.
//   256..383: tile 31-j, iters [16,32-j), PARTIAL -> ws + qn1.
// fallback (grid 256): full tiles, DIRECT.
__global__ __launch_bounds__(256, 2) void mlstm_main(
    const float* __restrict__ qg,
    const char* __restrict__ gkh, const char* __restrict__ gkl,
    const char* __restrict__ gvh, const char* __restrict__ gvl,
    const float* __restrict__ bf, const float* __restrict__ Mf,
    const float* __restrict__ en, float* __restrict__ outg,
    float* __restrict__ qn0, float* __restrict__ qn1,
    float* __restrict__ partials, int use_split)
{
  __shared__ char smem[SMEM_MAIN];
  const int bid  = blockIdx.x;
  const int hd   = bid & 7;            // head i -> XCD i (L2-resident panels)
  int tile, it0, nit, mode;            // mode: 0 direct, 1 raw, 2 partial
  if (!use_split) {
    tile = bid >> 3; it0 = 0; nit = tile + 1; mode = 0;
  } else if (bid < 128) {
    tile = bid >> 3; it0 = 0; nit = tile + 1; mode = 0;
  } else if (bid < 256) {
    tile = 31 - ((bid >> 3) - 16); it0 = 0; nit = 16; mode = 1;
  } else {
    const int j = (bid - 256) >> 3; tile = 31 - j; it0 = 16; nit = 16 - j; mode = 2;
  }
  const int t0   = tile * 64;
  const int tid  = threadIdx.x;
  const int w    = tid >> 6;
  const int lane = tid & 63;
  const int c    = lane & 15;
  const int g    = lane >> 4;
  const int wk   = w & 1;              // kv half (32 rows)
  const int qp   = w >> 1;             // q-subtile pair {2qp, 2qp+1}

  const size_t hbase = (size_t)hd * S_LEN;
  const char* pkh = gkh + hbase * 256;         // per-head K panel (512KB)
  const char* pkl = gkl + hbase * 256;
  const char* pvh = gvh + (size_t)hd * 524288; // per-head VT panel (512KB)
  const char* pvl = gvl + (size_t)hd * 524288;

  // ---- Q fragments (hi/lo split), scaled ----
  constexpr float QSC = 0.08838834764831845f;
  f16x8 qfh[2][4], qfl[2][4];
#pragma unroll
  for (int u = 0; u < 2; ++u) {
    const float* qrow = qg + (hbase + t0 + 16 * (2 * qp + u) + c) * DHD;
#pragma unroll
    for (int kc = 0; kc < 4; ++kc) {
      const float* p = qrow + kc * 32 + 8 * g;
      float4 a = *(const float4*)p;
      float4 b = *(const float4*)(p + 4);
      float xs[8] = {a.x, a.y, a.z, a.w, b.x, b.y, b.z, b.w};
#pragma unroll
      for (int s = 0; s < 8; ++s) {
        float x = xs[s] * QSC;
        f16 hi = (f16)x;
        qfh[u][kc][s] = hi;
        qfl[u][kc][s] = (f16)(x - (float)hi);
      }
    }
  }
  float Mq[2];
  Mq[0] = Mf[hbase + t0 + 16 * (2 * qp) + c];
  Mq[1] = Mf[hbase + t0 + 16 * (2 * qp + 1) + c];

  const f32x4 z4 = {0.f, 0.f, 0.f, 0.f};
  f32x4 hacc[2][8];
#pragma unroll
  for (int u = 0; u < 2; ++u)
#pragma unroll
    for (int et = 0; et < 8; ++et) hacc[u][et] = z4;
  float qn[2] = {0.f, 0.f};

  for (int it = it0; it < it0 + nit; ++it) {
    const int s0 = it * 64;
    __syncthreads();   // prior iteration's fragment reads done before restage

    // ---- stage 64KB via global_load_lds (pure memcpy) ----
    {
      const size_t tb = (size_t)it * 16384;
#pragma unroll
      for (int u = 0; u < 4; ++u) {
        const int off = (w << 12) + (u << 10);
        const int gl  = off + lane * 16;
        gload16(pkh + tb + gl, smem + KHI + off);
        gload16(pkl + tb + gl, smem + KLO + off);
        gload16(pvh + tb + gl, smem + VHI + off);
        gload16(pvl + tb + gl, smem + VLO + off);
      }
    }
    f32x4 b0 = *(const f32x4*)(bf + hbase + s0 + 32 * wk + 4 * g);
    f32x4 b1 = *(const f32x4*)(bf + hbase + s0 + 32 * wk + 16 + 4 * g);
    __syncthreads();   // own vmcnt drained before barrier -> staged data ready

    // ---- swapped QK^T: D = mfma(K, Q); lane: q=c, kv=32wk+{4g+r,16+4g+r} --
    f32x4 sacc[2][2];
    sacc[0][0] = z4; sacc[0][1] = z4; sacc[1][0] = z4; sacc[1][1] = z4;
#pragma unroll
    for (int kc = 0; kc < 4; ++kc) {
      const int cb = kc * 64 + 16 * g;
      f16x8 kh0 = *(const f16x8*)(smem + KHI + kswz(32 * wk + c,      cb));
      f16x8 kl0 = *(const f16x8*)(smem + KLO + kswz(32 * wk + c,      cb));
      f16x8 kh1 = *(const f16x8*)(smem + KHI + kswz(32 * wk + 16 + c, cb));
      f16x8 kl1 = *(const f16x8*)(smem + KLO + kswz(32 * wk + 16 + c, cb));
#pragma unroll
      for (int u = 0; u < 2; ++u) {
        sacc[u][0] = mfma16(kh0, qfh[u][kc], sacc[u][0]);
        sacc[u][0] = mfma16(kh0, qfl[u][kc], sacc[u][0]);
        sacc[u][0] = mfma16(kl0, qfh[u][kc], sacc[u][0]);
        sacc[u][1] = mfma16(kh1, qfh[u][kc], sacc[u][1]);
        sacc[u][1] = mfma16(kh1, qfl[u][kc], sacc[u][1]);
        sacc[u][1] = mfma16(kl1, qfh[u][kc], sacc[u][1]);
      }
    }

    // ---- P = exp(b_s - M_q) * S, causal mask, split to fp16 frags ----
    f16x8 pfh[2], pfl[2];
#pragma unroll
    for (int u = 0; u < 2; ++u) {
      const int qglob = t0 + 16 * (2 * qp + u) + c;
#pragma unroll
      for (int r = 0; r < 4; ++r) {
        const int kv0 = s0 + 32 * wk + 4 * g + r;
        const int kv1 = kv0 + 16;
        float p0 = (kv0 <= qglob) ? __expf(b0[r] - Mq[u]) * sacc[u][0][r] : 0.f;
        float p1 = (kv1 <= qglob) ? __expf(b1[r] - Mq[u]) * sacc[u][1][r] : 0.f;
        qn[u] += p0 + p1;
        f16 h0 = (f16)p0; pfh[u][r]     = h0; pfl[u][r]     = (f16)(p0 - (float)h0);
        f16 h1 = (f16)p1; pfh[u][r + 4] = h1; pfl[u][r + 4] = (f16)(p1 - (float)h1);
      }
    }

    // ---- PV: A = P (in-register), B = V^T frags from LDS ----
    const int byte0 = (64 * wk + 8 * g)      ^ (c << 3);
    const int byte1 = (64 * wk + 32 + 8 * g) ^ (c << 3);
#pragma unroll
    for (int et = 0; et < 8; ++et) {
      const int eb = (16 * et + c) * 128;
      f16x4 vh0 = *(const f16x4*)(smem + VHI + eb + byte0);
      f16x4 vh1 = *(const f16x4*)(smem + VHI + eb + byte1);
      f16x4 vl0 = *(const f16x4*)(smem + VLO + eb + byte0);
      f16x4 vl1 = *(const f16x4*)(smem + VLO + eb + byte1);
      f16x8 vfh, vfl;
#pragma unroll
      for (int s = 0; s < 4; ++s) {
        vfh[s] = vh0[s]; vfh[s + 4] = vh1[s];
        vfl[s] = vl0[s]; vfl[s + 4] = vl1[s];
      }
#pragma unroll
      for (int u = 0; u < 2; ++u) {
        hacc[u][et] = mfma16(pfh[u], vfh, hacc[u][et]);
        hacc[u][et] = mfma16(pfh[u], vfl, hacc[u][et]);
        hacc[u][et] = mfma16(pfl[u], vfh, hacc[u][et]);
      }
    }
  }

  // ---- epilogue: qn wave-reduce, then two 32-row reduce/store rounds ----
#pragma unroll
  for (int u = 0; u < 2; ++u) {
    qn[u] += __shfl_xor(qn[u], 16);
    qn[u] += __shfl_xor(qn[u], 32);
  }
  float* part = (float*)smem;                 // [2 wk][32 q][132]
  float* qnl  = (float*)(smem + QNL_OFF);     // [2 wk][2 u][16]
  const int pslot = hd * 16 + (tile - 16);    // valid for modes 1/2

#pragma unroll
  for (int round = 0; round < 2; ++round) {
    __syncthreads();  // prior reads of smem done (loop frags / round A stores)
    if (qp == round) {
      if (lane < 16) {
        qnl[(wk * 2 + 0) * 16 + lane] = qn[0];
        qnl[(wk * 2 + 1) * 16 + lane] = qn[1];
      }
#pragma unroll
      for (int u = 0; u < 2; ++u)
#pragma unroll
        for (int et = 0; et < 8; ++et)
#pragma unroll
          for (int r = 0; r < 4; ++r)
            part[(wk * 32 + 16 * u + 4 * g + r) * 132 + 16 * et + c] = hacc[u][et][r];
    }
    __syncthreads();

    const int q32  = tid >> 3;            // 0..31
    const int cseg = (tid & 7) * 16;      // 16 floats (4 float4)
    const int rowg = t0 + round * 32 + q32;
    const float qns = qnl[(q32 >> 4) * 16 + (q32 & 15)] +
                      qnl[(2 + (q32 >> 4)) * 16 + (q32 & 15)];
    const float* pa = part + q32 * 132 + cseg;
    const float* pb = part + (32 + q32) * 132 + cseg;
    float4 s[4];
#pragma unroll
    for (int k = 0; k < 4; ++k) {
      float4 a = *(const float4*)(pa + 4 * k);
      float4 b = *(const float4*)(pb + 4 * k);
      s[k] = make_float4(a.x + b.x, a.y + b.y, a.z + b.z, a.w + b.w);
    }
    if (mode == 0) {
      const float den = fmaxf(fabsf(qns), en[hbase + rowg]) + EPS;
      const float inv = 1.0f / den;
      float* dst = outg + (hbase + rowg) * DHD + cseg;
#pragma unroll
      for (int k = 0; k < 4; ++k)
        *(float4*)(dst + 4 * k) = make_float4(s[k].x * inv, s[k].y * inv, s[k].z * inv, s[k].w * inv);
    } else if (mode == 1) {
      float* dst = outg + (hbase + rowg) * DHD + cseg;
#pragma unroll
      for (int k = 0; k < 4; ++k) *(float4*)(dst + 4 * k) = s[k];
      if ((tid & 7) == 0) qn0[pslot * 64 + round * 32 + q32] = qns;
    } else {
      float* dst = partials + ((size_t)pslot * 64 + round * 32 + q32) * DHD + cseg;
#pragma unroll
      for (int k = 0; k < 4; ++k) *(float4*)(dst + 4 * k) = s[k];
      if ((tid & 7) == 0) qn1[pslot * 64 + round * 32 + q32] = qns;
    }
  }
}

// ---------------- merge kernel: split tiles (16..31) only ------------------
__global__ __launch_bounds__(256) void mlstm_merge(
    float* __restrict__ outg, const float* __restrict__ partials,
    const float* __restrict__ qn0, const float* __restrict__ qn1,
    const float* __restrict__ en)
{
  const int pslot = blockIdx.x;        // 0..127 = head*16 + (tile-16)
  const int h     = pslot >> 4;
  const int tile  = 16 + (pslot & 15);
  const size_t rowbase = (size_t)h * S_LEN + tile * 64;
  const int tid = threadIdx.x;
  const int r   = tid >> 2;            // 0..63
  const int c4  = (tid & 3) * 32;      // 32 floats
  const float qns = qn0[pslot * 64 + r] + qn1[pslot * 64 + r];
  const float den = fmaxf(fabsf(qns), en[rowbase + r]) + EPS;
  const float inv = 1.0f / den;
  float* orow = outg + (rowbase + r) * DHD + c4;
  const float* prow = partials + ((size_t)pslot * 64 + r) * DHD + c4;
#pragma unroll
  for (int k = 0; k < 8; ++k) {
    float4 a = *(const float4*)(orow + 4 * k);
    float4 b = *(const float4*)(prow + 4 * k);
    *(float4*)(orow + 4 * k) =
        make_float4((a.x + b.x) * inv, (a.y + b.y) * inv, (a.z + b.z) * inv, (a.w + b.w) * inv);
  }
}

extern "C" void kernel_launch(void* const* d_in, const int* in_sizes, int n_in,
                              void* d_out, int out_size, void* d_ws, size_t ws_size,
                              hipStream_t stream) {
  (void)in_sizes; (void)n_in; (void)out_size;
  const float* q  = (const float*)d_in[0];
  const float* k  = (const float*)d_in[1];
  const float* v  = (const float*)d_in[2];
  const float* ii = (const float*)d_in[3];
  const float* ff = (const float*)d_in[4];
  float* out = (float*)d_out;

  float* bf = (float*)d_ws;                  // f32 [8][2048]
  float* Mf = bf + NHEADS * S_LEN;
  float* en = Mf + NHEADS * S_LEN;           // ends at 192KB

  const size_t PANEL = 4u * 1024 * 1024;
  char* gkh = (char*)(en + NHEADS * S_LEN);
  char* gkl = gkh + PANEL;
  char* gvh = gkl + PANEL;
  char* gvl = gvh + PANEL;                   // ends at 192KB + 16MB
  float* qn0 = (float*)(gvl + PANEL);        // 128*64 f32
  float* qn1 = qn0 + 128 * 64;
  float* partials = qn1 + 128 * 64;          // 128*64*128 f32 = 4MB

  const size_t need = 3u * NHEADS * S_LEN * 4 + 4 * PANEL
                    + 2u * 128 * 64 * 4 + (size_t)128 * 64 * DHD * 4;
  const int use_split = (ws_size >= need) ? 1 : 0;

  mlstm_pre<<<dim3(520), dim3(256), 0, stream>>>(k, v, ii, ff,
                                                 gkh, gkl, gvh, gvl, bf, Mf, en);
  mlstm_main<<<dim3(use_split ? 384 : 256), dim3(256), 0, stream>>>(
      q, gkh, gkl, gvh, gvl, bf, Mf, en, out, qn0, qn1, partials, use_split);
  if (use_split)
    mlstm_merge<<<dim3(128), dim3(256), 0, stream>>>(out, partials, qn0, qn1, en);
}